// Round 1
// baseline (2585.663 us; speedup 1.0000x reference)
//
#include <hip/hip_runtime.h>

#define CC 128   // all channel dims are 128

// ---------------- degree / dinv ----------------
__global__ __launch_bounds__(256) void count_deg(const int* __restrict__ dst,
                                                 int* __restrict__ deg, int e) {
    int i = blockIdx.x * 256 + threadIdx.x;
    if (i < e) atomicAdd(&deg[dst[i]], 1);
}

__global__ __launch_bounds__(256) void make_dinv(float* __restrict__ dinv, int n) {
    int i = blockIdx.x * 256 + threadIdx.x;
    if (i < n) {
        int d = ((const int*)dinv)[i];
        dinv[i] = rsqrtf((float)d + 1.0f);
    }
}

// ---------------- GEMM: Y[n,128] = X[n,128] @ W[128,128] ----------------
// 8 rows per block, 256 threads: thread = (row 0..7) x (col-group 0..31, float4)
__global__ __launch_bounds__(256) void gemm128(const float* __restrict__ X,
                                               const float* __restrict__ W,
                                               float* __restrict__ Y, int n) {
    __shared__ float sW[CC * CC];   // 64 KB
    __shared__ float sX[8 * CC];    // 4 KB
    for (int i = threadIdx.x; i < CC * CC / 4; i += 256)
        ((float4*)sW)[i] = ((const float4*)W)[i];
    int row0 = blockIdx.x * 8;
    int srow = row0 + (threadIdx.x >> 5);
    if (srow < n)
        ((float4*)sX)[threadIdx.x] = ((const float4*)(X + (size_t)row0 * CC))[threadIdx.x];
    __syncthreads();

    int rl = threadIdx.x >> 5;   // local row 0..7
    int cg = threadIdx.x & 31;   // float4 col group
    int r = row0 + rl;
    if (r >= n) return;
    const float* xr = sX + rl * CC;
    float4 acc = {0.f, 0.f, 0.f, 0.f};
#pragma unroll 4
    for (int k = 0; k < CC; ++k) {
        float xv = xr[k];
        float4 w = ((const float4*)(sW + k * CC))[cg];
        acc.x = fmaf(xv, w.x, acc.x);
        acc.y = fmaf(xv, w.y, acc.y);
        acc.z = fmaf(xv, w.z, acc.z);
        acc.w = fmaf(xv, w.w, acc.w);
    }
    ((float4*)(Y + (size_t)r * CC))[cg] = acc;
}

// ---------------- edge aggregation: AGG[dst] += H[src] * dinv[src]*dinv[dst] ----
// 32 threads per edge, float4 per thread, scalar float atomics.
__global__ __launch_bounds__(256) void aggregate(const float* __restrict__ H,
                                                 const int* __restrict__ src,
                                                 const int* __restrict__ dst,
                                                 const float* __restrict__ dinv,
                                                 float* __restrict__ AGG, int e) {
    long long t = (long long)blockIdx.x * 256 + threadIdx.x;
    int ei = (int)(t >> 5);
    if (ei >= e) return;
    int j = (int)(t & 31);
    int s = src[ei], d = dst[ei];
    float norm = dinv[s] * dinv[d];
    float4 hv = ((const float4*)(H + (size_t)s * CC))[j];
    float* ap = AGG + (size_t)d * CC + j * 4;
    atomicAdd(ap + 0, hv.x * norm);
    atomicAdd(ap + 1, hv.y * norm);
    atomicAdd(ap + 2, hv.z * norm);
    atomicAdd(ap + 3, hv.w * norm);
}

// ---------------- OUT += H * dinv^2 + b (elementwise, in-place on OUT) --------
__global__ __launch_bounds__(256) void add_self_bias(float* __restrict__ OUT,
                                                     const float* __restrict__ H,
                                                     const float* __restrict__ dinv,
                                                     const float* __restrict__ b, int n) {
    int t = blockIdx.x * 256 + threadIdx.x;
    int total = n * (CC / 4);
    if (t >= total) return;
    int i = t >> 5;
    int j = t & 31;
    float di = dinv[i];
    float sl = di * di;
    float4 h = ((const float4*)(H + (size_t)i * CC))[j];
    float4 o = ((const float4*)(OUT + (size_t)i * CC))[j];
    float4 bb = ((const float4*)b)[j];
    o.x += h.x * sl + bb.x;
    o.y += h.y * sl + bb.y;
    o.z += h.z * sl + bb.z;
    o.w += h.w * sl + bb.w;
    ((float4*)(OUT + (size_t)i * CC))[j] = o;
}

// ---------------- BN column stats: sums[c], sums[128+c] = sum, sumsq ----------
__global__ __launch_bounds__(256) void bn_stats(const float* __restrict__ X,
                                                float* __restrict__ sums, int n) {
    int c = threadIdx.x & 127;
    int rs = threadIdx.x >> 7;  // 0..1
    float s = 0.f, q = 0.f;
    for (int r = blockIdx.x * 2 + rs; r < n; r += gridDim.x * 2) {
        float v = X[(size_t)r * CC + c];
        s += v;
        q = fmaf(v, v, q);
    }
    atomicAdd(&sums[c], s);
    atomicAdd(&sums[CC + c], q);
}

// ---------------- Y = relu((X - mean) * rsqrt(var+eps) * gamma + beta) --------
__global__ __launch_bounds__(256) void bn_relu(const float* __restrict__ X,
                                               float* __restrict__ Y,
                                               const float* __restrict__ sums,
                                               const float* __restrict__ gamma,
                                               const float* __restrict__ beta, int n) {
    int t = blockIdx.x * 256 + threadIdx.x;
    int total = n * (CC / 4);
    if (t >= total) return;
    int i = t >> 5;
    int j = t & 31;
    float inv_n = 1.0f / (float)n;
    float4 x  = ((const float4*)(X + (size_t)i * CC))[j];
    float4 sm = ((const float4*)sums)[j];
    float4 sq = ((const float4*)(sums + CC))[j];
    float4 g  = ((const float4*)gamma)[j];
    float4 be = ((const float4*)beta)[j];
    float4 y;
    {
        float mean = sm.x * inv_n, var = sq.x * inv_n - mean * mean;
        float sc = g.x * rsqrtf(var + 1e-5f);
        y.x = fmaxf(0.f, (x.x - mean) * sc + be.x);
    }
    {
        float mean = sm.y * inv_n, var = sq.y * inv_n - mean * mean;
        float sc = g.y * rsqrtf(var + 1e-5f);
        y.y = fmaxf(0.f, (x.y - mean) * sc + be.y);
    }
    {
        float mean = sm.z * inv_n, var = sq.z * inv_n - mean * mean;
        float sc = g.z * rsqrtf(var + 1e-5f);
        y.z = fmaxf(0.f, (x.z - mean) * sc + be.z);
    }
    {
        float mean = sm.w * inv_n, var = sq.w * inv_n - mean * mean;
        float sc = g.w * rsqrtf(var + 1e-5f);
        y.w = fmaxf(0.f, (x.w - mean) * sc + be.w);
    }
    ((float4*)(Y + (size_t)i * CC))[j] = y;
}

extern "C" void kernel_launch(void* const* d_in, const int* in_sizes, int n_in,
                              void* d_out, int out_size, void* d_ws, size_t ws_size,
                              hipStream_t stream) {
    const float* x      = (const float*)d_in[0];
    const float* W1     = (const float*)d_in[1];
    const float* b1     = (const float*)d_in[2];
    const float* gamma1 = (const float*)d_in[3];
    const float* beta1  = (const float*)d_in[4];
    const float* W2     = (const float*)d_in[5];
    const float* b2     = (const float*)d_in[6];
    const int*   edge   = (const int*)d_in[7];

    int n = in_sizes[0] / CC;
    int e = in_sizes[7] / 2;
    const int* src = edge;
    const int* dst = edge + e;

    float* out   = (float*)d_out;
    char*  ws    = (char*)d_ws;
    float* h_scr = (float*)ws;                                      // n*128 f32
    float* dinv  = (float*)(ws + (size_t)n * CC * 4);               // n f32
    float* sums  = (float*)(ws + (size_t)n * CC * 4 + (size_t)n * 4); // 256 f32

    int tot4 = n * (CC / 4);
    int gemm_grid = (n + 7) / 8;
    long long agg_threads = (long long)e * 32;
    int agg_grid = (int)((agg_threads + 255) / 256);

    // degree -> dinv  (deg stored as int in dinv buffer, converted in place)
    hipMemsetAsync(dinv, 0, (size_t)n * 4, stream);
    count_deg<<<(e + 255) / 256, 256, 0, stream>>>(dst, (int*)dinv, e);
    make_dinv<<<(n + 255) / 256, 256, 0, stream>>>(dinv, n);

    // layer 1: h1 = x@W1 -> out (scratch use of d_out)
    gemm128<<<gemm_grid, 256, 0, stream>>>(x, W1, out, n);
    hipMemsetAsync(h_scr, 0, (size_t)n * CC * 4, stream);
    aggregate<<<agg_grid, 256, 0, stream>>>(out, src, dst, dinv, h_scr, e);
    add_self_bias<<<(tot4 + 255) / 256, 256, 0, stream>>>(h_scr, out, dinv, b1, n);

    // batchnorm + relu: h -> out
    hipMemsetAsync(sums, 0, 2 * CC * 4, stream);
    bn_stats<<<512, 256, 0, stream>>>(h_scr, sums, n);
    bn_relu<<<(tot4 + 255) / 256, 256, 0, stream>>>(h_scr, out, sums, gamma1, beta1, n);

    // layer 2: h2 = h@W2 -> h_scr
    gemm128<<<gemm_grid, 256, 0, stream>>>(out, W2, h_scr, n);
    hipMemsetAsync(out, 0, (size_t)n * CC * 4, stream);
    aggregate<<<agg_grid, 256, 0, stream>>>(h_scr, src, dst, dinv, out, e);
    add_self_bias<<<(tot4 + 255) / 256, 256, 0, stream>>>(out, h_scr, dinv, b2, n);
}

// Round 2
// 573.705 us; speedup vs baseline: 4.5070x; 4.5070x over previous
//
#include <hip/hip_runtime.h>

#define CC 128      // all channel dims are 128
#define TILE 1024   // scan tile

// ---------------- degree ----------------
__global__ __launch_bounds__(256) void count_deg(const int* __restrict__ dst,
                                                 int* __restrict__ deg, int e) {
    int i = blockIdx.x * 256 + threadIdx.x;
    if (i < e) atomicAdd(&deg[dst[i]], 1);
}

__global__ __launch_bounds__(256) void make_dinv(const int* __restrict__ deg,
                                                 float* __restrict__ dinv, int n) {
    int i = blockIdx.x * 256 + threadIdx.x;
    if (i < n) dinv[i] = rsqrtf((float)deg[i] + 1.0f);
}

// ---------------- exclusive scan over deg -> rowptr (3 kernels) ----------------
__global__ __launch_bounds__(256) void scan_tile_sums(const int* __restrict__ deg,
                                                      int* __restrict__ tsum, int n) {
    __shared__ int red[256];
    int base = blockIdx.x * TILE;
    int s = 0;
    for (int i = threadIdx.x; i < TILE; i += 256) {
        int g = base + i;
        s += (g < n) ? deg[g] : 0;
    }
    red[threadIdx.x] = s;
    __syncthreads();
    for (int off = 128; off > 0; off >>= 1) {
        if (threadIdx.x < off) red[threadIdx.x] += red[threadIdx.x + off];
        __syncthreads();
    }
    if (threadIdx.x == 0) tsum[blockIdx.x] = red[0];
}

__global__ void scan_tops(int* __restrict__ tsum, int nt) {
    if (threadIdx.x == 0 && blockIdx.x == 0) {
        int acc = 0;
        for (int i = 0; i < nt; ++i) { int v = tsum[i]; tsum[i] = acc; acc += v; }
    }
}

__global__ __launch_bounds__(256) void scan_final(const int* __restrict__ deg,
                                                  const int* __restrict__ tsum,
                                                  int* __restrict__ rowptr,
                                                  int* __restrict__ cursor, int n) {
    __shared__ int lds[256];
    int base = blockIdx.x * TILE;
    int t = threadIdx.x;
    int g0 = base + t * 4;
    int v[4];
#pragma unroll
    for (int k = 0; k < 4; ++k) {
        int g = g0 + k;
        v[k] = (g < n) ? deg[g] : 0;
    }
    int tl = v[0] + v[1] + v[2] + v[3];
    lds[t] = tl;
    __syncthreads();
    for (int off = 1; off < 256; off <<= 1) {
        int add = (t >= off) ? lds[t - off] : 0;
        __syncthreads();
        lds[t] += add;
        __syncthreads();
    }
    int excl = lds[t] - tl + tsum[blockIdx.x];
#pragma unroll
    for (int k = 0; k < 4; ++k) {
        int g = g0 + k;
        if (g < n) {
            rowptr[g] = excl;
            cursor[g] = excl;
            if (g == n - 1) rowptr[n] = excl + v[k];
            excl += v[k];
        }
    }
}

// ---------------- CSR fill: csr[slot] = src, grouped by dst ----------------
__global__ __launch_bounds__(256) void fill_csr(const int* __restrict__ src,
                                                const int* __restrict__ dst,
                                                int* __restrict__ cursor,
                                                int* __restrict__ csr, int e) {
    int i = blockIdx.x * 256 + threadIdx.x;
    if (i < e) {
        int slot = atomicAdd(&cursor[dst[i]], 1);
        csr[slot] = src[i];
    }
}

// ---------------- GEMM: Y[n,128] = (X[n,128] @ W[128,128]) * dinv[row] ----------
__global__ __launch_bounds__(256) void gemm128(const float* __restrict__ X,
                                               const float* __restrict__ W,
                                               const float* __restrict__ dinv,
                                               float* __restrict__ Y, int n) {
    __shared__ float sW[CC * CC];   // 64 KB
    __shared__ float sX[8 * CC];    // 4 KB
    for (int i = threadIdx.x; i < CC * CC / 4; i += 256)
        ((float4*)sW)[i] = ((const float4*)W)[i];
    int row0 = blockIdx.x * 8;
    int srow = row0 + (threadIdx.x >> 5);
    if (srow < n)
        ((float4*)sX)[threadIdx.x] = ((const float4*)(X + (size_t)row0 * CC))[threadIdx.x];
    __syncthreads();

    int rl = threadIdx.x >> 5;   // local row 0..7
    int cg = threadIdx.x & 31;   // float4 col group
    int r = row0 + rl;
    if (r >= n) return;
    const float* xr = sX + rl * CC;
    float4 acc = {0.f, 0.f, 0.f, 0.f};
#pragma unroll 4
    for (int k = 0; k < CC; ++k) {
        float xv = xr[k];
        float4 w = ((const float4*)(sW + k * CC))[cg];
        acc.x = fmaf(xv, w.x, acc.x);
        acc.y = fmaf(xv, w.y, acc.y);
        acc.z = fmaf(xv, w.z, acc.z);
        acc.w = fmaf(xv, w.w, acc.w);
    }
    float dv = dinv[r];
    acc.x *= dv; acc.y *= dv; acc.z *= dv; acc.w *= dv;
    ((float4*)(Y + (size_t)r * CC))[cg] = acc;
}

// ---------------- CSR aggregation, fused self-loop + dinv scale + bias --------
// OUT[d] = dinv[d] * (HS[d] + sum_{s in N(d)} HS[s]) + bias
__global__ __launch_bounds__(256) void aggregate_csr(const float* __restrict__ HS,
                                                     const int* __restrict__ rowptr,
                                                     const int* __restrict__ csr,
                                                     const float* __restrict__ dinv,
                                                     const float* __restrict__ bias,
                                                     float* __restrict__ OUT, int n) {
    int d = blockIdx.x * 8 + (threadIdx.x >> 5);
    if (d >= n) return;
    int j = threadIdx.x & 31;
    float4 acc = ((const float4*)(HS + (size_t)d * CC))[j];   // self term
    int k = rowptr[d], end = rowptr[d + 1];
    for (; k < end; ++k) {
        int s = csr[k];
        float4 v = ((const float4*)(HS + (size_t)s * CC))[j];
        acc.x += v.x; acc.y += v.y; acc.z += v.z; acc.w += v.w;
    }
    float dd = dinv[d];
    float4 b = ((const float4*)bias)[j];
    acc.x = fmaf(acc.x, dd, b.x);
    acc.y = fmaf(acc.y, dd, b.y);
    acc.z = fmaf(acc.z, dd, b.z);
    acc.w = fmaf(acc.w, dd, b.w);
    ((float4*)(OUT + (size_t)d * CC))[j] = acc;
}

// ---------------- BN column stats ----------------
__global__ __launch_bounds__(256) void bn_stats(const float* __restrict__ X,
                                                float* __restrict__ sums, int n) {
    int c = threadIdx.x & 127;
    int rs = threadIdx.x >> 7;
    float s = 0.f, q = 0.f;
    for (int r = blockIdx.x * 2 + rs; r < n; r += gridDim.x * 2) {
        float v = X[(size_t)r * CC + c];
        s += v;
        q = fmaf(v, v, q);
    }
    atomicAdd(&sums[c], s);
    atomicAdd(&sums[CC + c], q);
}

// ---------------- BN + ReLU ----------------
__global__ __launch_bounds__(256) void bn_relu(const float* __restrict__ X,
                                               float* __restrict__ Y,
                                               const float* __restrict__ sums,
                                               const float* __restrict__ gamma,
                                               const float* __restrict__ beta, int n) {
    int t = blockIdx.x * 256 + threadIdx.x;
    int total = n * (CC / 4);
    if (t >= total) return;
    int i = t >> 5;
    int j = t & 31;
    float inv_n = 1.0f / (float)n;
    float4 x  = ((const float4*)(X + (size_t)i * CC))[j];
    float4 sm = ((const float4*)sums)[j];
    float4 sq = ((const float4*)(sums + CC))[j];
    float4 g  = ((const float4*)gamma)[j];
    float4 be = ((const float4*)beta)[j];
    float4 y;
    {
        float mean = sm.x * inv_n, var = sq.x * inv_n - mean * mean;
        float sc = g.x * rsqrtf(var + 1e-5f);
        y.x = fmaxf(0.f, (x.x - mean) * sc + be.x);
    }
    {
        float mean = sm.y * inv_n, var = sq.y * inv_n - mean * mean;
        float sc = g.y * rsqrtf(var + 1e-5f);
        y.y = fmaxf(0.f, (x.y - mean) * sc + be.y);
    }
    {
        float mean = sm.z * inv_n, var = sq.z * inv_n - mean * mean;
        float sc = g.z * rsqrtf(var + 1e-5f);
        y.z = fmaxf(0.f, (x.z - mean) * sc + be.z);
    }
    {
        float mean = sm.w * inv_n, var = sq.w * inv_n - mean * mean;
        float sc = g.w * rsqrtf(var + 1e-5f);
        y.w = fmaxf(0.f, (x.w - mean) * sc + be.w);
    }
    ((float4*)(Y + (size_t)i * CC))[j] = y;
}

extern "C" void kernel_launch(void* const* d_in, const int* in_sizes, int n_in,
                              void* d_out, int out_size, void* d_ws, size_t ws_size,
                              hipStream_t stream) {
    const float* x      = (const float*)d_in[0];
    const float* W1     = (const float*)d_in[1];
    const float* b1     = (const float*)d_in[2];
    const float* gamma1 = (const float*)d_in[3];
    const float* beta1  = (const float*)d_in[4];
    const float* W2     = (const float*)d_in[5];
    const float* b2     = (const float*)d_in[6];
    const int*   edge   = (const int*)d_in[7];

    int n = in_sizes[0] / CC;
    int e = in_sizes[7] / 2;
    const int* src = edge;
    const int* dst = edge + e;

    float* out = (float*)d_out;           // also used as scratch O
    char*  ws  = (char*)d_ws;
    float* A       = (float*)ws;                                   ws += (size_t)n * CC * 4;
    int*   deg     = (int*)ws;                                     ws += (size_t)n * 4;
    float* dinv    = (float*)ws;                                   ws += (size_t)n * 4;
    int*   rowptr  = (int*)ws;                                     ws += (size_t)(n + 1) * 4;
    int*   cursor  = (int*)ws;                                     ws += (size_t)n * 4;
    int*   csr     = (int*)ws;                                     ws += (size_t)e * 4;
    int*   tsum    = (int*)ws;                                     ws += 4096;
    float* sums    = (float*)ws;

    int ntiles = (n + TILE - 1) / TILE;
    int tot4 = n * (CC / 4);
    int gemm_grid = (n + 7) / 8;
    int agg_grid = (n + 7) / 8;

    // ---- graph structure (per call, deterministic) ----
    hipMemsetAsync(deg, 0, (size_t)n * 4, stream);
    count_deg<<<(e + 255) / 256, 256, 0, stream>>>(dst, deg, e);
    make_dinv<<<(n + 255) / 256, 256, 0, stream>>>(deg, dinv, n);
    scan_tile_sums<<<ntiles, 256, 0, stream>>>(deg, tsum, n);
    scan_tops<<<1, 64, 0, stream>>>(tsum, ntiles);
    scan_final<<<ntiles, 256, 0, stream>>>(deg, tsum, rowptr, cursor, n);
    fill_csr<<<(e + 255) / 256, 256, 0, stream>>>(src, dst, cursor, csr, e);

    // ---- layer 1: hs1 = (x@W1)*dinv -> out(scratch); h1 -> A ----
    gemm128<<<gemm_grid, 256, 0, stream>>>(x, W1, dinv, out, n);
    aggregate_csr<<<agg_grid, 256, 0, stream>>>(out, rowptr, csr, dinv, b1, A, n);

    // ---- batchnorm + relu: A -> out(scratch) ----
    hipMemsetAsync(sums, 0, 2 * CC * 4, stream);
    bn_stats<<<512, 256, 0, stream>>>(A, sums, n);
    bn_relu<<<(tot4 + 255) / 256, 256, 0, stream>>>(A, out, sums, gamma1, beta1, n);

    // ---- layer 2: hs2 = (hbn@W2)*dinv -> A; final -> out ----
    gemm128<<<gemm_grid, 256, 0, stream>>>(out, W2, dinv, A, n);
    aggregate_csr<<<agg_grid, 256, 0, stream>>>(A, rowptr, csr, dinv, b2, out, n);
}

// Round 3
// 295.050 us; speedup vs baseline: 8.7635x; 1.9444x over previous
//
#include <hip/hip_runtime.h>

#define CC 128      // all channel dims are 128
#define TILE 1024   // scan tile

typedef unsigned int uint;
typedef unsigned short ushort;
typedef __attribute__((ext_vector_type(8))) short short8;
typedef __attribute__((ext_vector_type(4))) float f32x4;

__device__ __forceinline__ ushort f2bf(float f) {
    uint u = __float_as_uint(f);
    u += 0x7FFFu + ((u >> 16) & 1u);   // round-to-nearest-even
    return (ushort)(u >> 16);
}
__device__ __forceinline__ float bf2f(ushort h) {
    return __uint_as_float(((uint)h) << 16);
}

// ---------------- degree ----------------
__global__ __launch_bounds__(256) void count_deg(const int* __restrict__ dst,
                                                 int* __restrict__ deg, int e) {
    int i = blockIdx.x * 256 + threadIdx.x;
    if (i < e) atomicAdd(&deg[dst[i]], 1);
}

__global__ __launch_bounds__(256) void make_dinv(const int* __restrict__ deg,
                                                 float* __restrict__ dinv, int n) {
    int i = blockIdx.x * 256 + threadIdx.x;
    if (i < n) dinv[i] = rsqrtf((float)deg[i] + 1.0f);
}

// ---------------- exclusive scan over deg -> rowptr ----------------
__global__ __launch_bounds__(256) void scan_tile_sums(const int* __restrict__ deg,
                                                      int* __restrict__ tsum, int n) {
    __shared__ int red[256];
    int base = blockIdx.x * TILE;
    int s = 0;
    for (int i = threadIdx.x; i < TILE; i += 256) {
        int g = base + i;
        s += (g < n) ? deg[g] : 0;
    }
    red[threadIdx.x] = s;
    __syncthreads();
    for (int off = 128; off > 0; off >>= 1) {
        if (threadIdx.x < off) red[threadIdx.x] += red[threadIdx.x + off];
        __syncthreads();
    }
    if (threadIdx.x == 0) tsum[blockIdx.x] = red[0];
}

// parallel exclusive scan of tile sums (nt <= 128)
__global__ __launch_bounds__(128) void scan_tops(int* __restrict__ tsum, int nt) {
    __shared__ int s[128];
    int t = threadIdx.x;
    int v = (t < nt) ? tsum[t] : 0;
    s[t] = v;
    __syncthreads();
    for (int off = 1; off < 128; off <<= 1) {
        int add = (t >= off) ? s[t - off] : 0;
        __syncthreads();
        s[t] += add;
        __syncthreads();
    }
    if (t < nt) tsum[t] = s[t] - v;   // exclusive
}

__global__ __launch_bounds__(256) void scan_final(const int* __restrict__ deg,
                                                  const int* __restrict__ tsum,
                                                  int* __restrict__ rowptr,
                                                  int* __restrict__ cursor, int n) {
    __shared__ int lds[256];
    int base = blockIdx.x * TILE;
    int t = threadIdx.x;
    int g0 = base + t * 4;
    int v[4];
#pragma unroll
    for (int k = 0; k < 4; ++k) {
        int g = g0 + k;
        v[k] = (g < n) ? deg[g] : 0;
    }
    int tl = v[0] + v[1] + v[2] + v[3];
    lds[t] = tl;
    __syncthreads();
    for (int off = 1; off < 256; off <<= 1) {
        int add = (t >= off) ? lds[t - off] : 0;
        __syncthreads();
        lds[t] += add;
        __syncthreads();
    }
    int excl = lds[t] - tl + tsum[blockIdx.x];
#pragma unroll
    for (int k = 0; k < 4; ++k) {
        int g = g0 + k;
        if (g < n) {
            rowptr[g] = excl;
            cursor[g] = excl;
            if (g == n - 1) rowptr[n] = excl + v[k];
            excl += v[k];
        }
    }
}

// ---------------- CSR fill ----------------
__global__ __launch_bounds__(256) void fill_csr(const int* __restrict__ src,
                                                const int* __restrict__ dst,
                                                int* __restrict__ cursor,
                                                int* __restrict__ csr, int e) {
    int i = blockIdx.x * 256 + threadIdx.x;
    if (i < e) {
        int slot = atomicAdd(&cursor[dst[i]], 1);
        csr[slot] = src[i];
    }
}

// ---------------- W[k][c] fp32 -> Wt[c][k] bf16 ----------------
__global__ __launch_bounds__(256) void convert_wT(const float* __restrict__ W,
                                                  ushort* __restrict__ Wt) {
    int t = blockIdx.x * 256 + threadIdx.x;   // 16384 total
    int k = t >> 7, c = t & 127;
    Wt[c * CC + k] = f2bf(W[k * CC + c]);
}

// ---------------- MFMA GEMM: Y[r][c] = bf16( dinv[r] * sum_k X[r][k]*W[k][c] ) --
// block: 128 rows x 128 cols, 256 threads (4 waves, each 32 rows x 128 cols).
// sA[row][k], sB[col][k] bf16 in LDS, XOR-swizzled: byte ^= ((row&7)<<4).
template <typename TIN>
__global__ __launch_bounds__(256) void gemm_mfma(const TIN* __restrict__ X,
                                                 const ushort* __restrict__ Wt,
                                                 const float* __restrict__ dinv,
                                                 ushort* __restrict__ Y, int n) {
    __shared__ ushort sA[CC * CC];   // 32 KB
    __shared__ ushort sB[CC * CC];   // 32 KB
    char* sAc = (char*)sA;
    char* sBc = (char*)sB;
    const int t = threadIdx.x;
    const int row0 = blockIdx.x * CC;

    // ---- stage A: X tile -> bf16, swizzled ----
    {
        int c8 = t & 15;          // 16B group (8 bf16)
        int rl = t >> 4;          // 0..15
#pragma unroll
        for (int it = 0; it < 8; ++it) {
            int r = rl + it * 16;
            int gr = row0 + r;
            short8 v;
            if (gr < n) {
                if constexpr (sizeof(TIN) == 4) {   // fp32 input
                    const float4* xp = (const float4*)(X + (size_t)gr * CC);
                    float4 lo = xp[c8 * 2], hi = xp[c8 * 2 + 1];
                    v[0] = (short)f2bf(lo.x); v[1] = (short)f2bf(lo.y);
                    v[2] = (short)f2bf(lo.z); v[3] = (short)f2bf(lo.w);
                    v[4] = (short)f2bf(hi.x); v[5] = (short)f2bf(hi.y);
                    v[6] = (short)f2bf(hi.z); v[7] = (short)f2bf(hi.w);
                } else {                            // bf16 input
                    v = *(const short8*)((const ushort*)X + (size_t)gr * CC + c8 * 8);
                }
            } else {
                v = short8{0, 0, 0, 0, 0, 0, 0, 0};
            }
            int byte = (r * CC + c8 * 8) * 2;
            byte ^= (r & 7) << 4;
            *(short8*)(sAc + byte) = v;
        }
    }
    // ---- stage B: Wt (bf16, already transposed) -> LDS, swizzled ----
    {
#pragma unroll
        for (int it = 0; it < 8; ++it) {
            int li = it * 256 + t;        // 16B units, 2048 total
            int r = li >> 4;              // col of W = row of Wt
            int c8 = li & 15;
            short8 v = *(const short8*)(Wt + r * CC + c8 * 8);
            int byte = (r * CC + c8 * 8) * 2;
            byte ^= (r & 7) << 4;
            *(short8*)(sBc + byte) = v;
        }
    }
    __syncthreads();

    const int wid = t >> 6;
    const int lane = t & 63;
    const int l15 = lane & 15;
    const int lhi = lane >> 4;           // 0..3
    const int wrow0 = wid * 32;

    f32x4 acc[2][8];
#pragma unroll
    for (int i = 0; i < 2; ++i)
#pragma unroll
        for (int j = 0; j < 8; ++j) acc[i][j] = f32x4{0.f, 0.f, 0.f, 0.f};

#pragma unroll
    for (int kc = 0; kc < 4; ++kc) {
        int koff = kc * 32 + lhi * 8;
        short8 a[2];
#pragma unroll
        for (int tm = 0; tm < 2; ++tm) {
            int r = wrow0 + tm * 16 + l15;
            int byte = (r * CC + koff) * 2;
            byte ^= (r & 7) << 4;
            a[tm] = *(const short8*)(sAc + byte);
        }
#pragma unroll
        for (int tn = 0; tn < 8; ++tn) {
            int rb = tn * 16 + l15;
            int byte = (rb * CC + koff) * 2;
            byte ^= (rb & 7) << 4;
            short8 b = *(const short8*)(sBc + byte);
            acc[0][tn] = __builtin_amdgcn_mfma_f32_16x16x32_bf16(a[0], b, acc[0][tn], 0, 0, 0);
            acc[1][tn] = __builtin_amdgcn_mfma_f32_16x16x32_bf16(a[1], b, acc[1][tn], 0, 0, 0);
        }
    }

    // ---- epilogue: scale by dinv[row], convert bf16, store ----
#pragma unroll
    for (int tm = 0; tm < 2; ++tm) {
        float dv[4];
        int rbase = row0 + wrow0 + tm * 16 + lhi * 4;
#pragma unroll
        for (int i = 0; i < 4; ++i)
            dv[i] = (rbase + i < n) ? dinv[rbase + i] : 0.f;
#pragma unroll
        for (int tn = 0; tn < 8; ++tn) {
            int col = tn * 16 + l15;
#pragma unroll
            for (int i = 0; i < 4; ++i) {
                int r = rbase + i;
                if (r < n) Y[(size_t)r * CC + col] = f2bf(acc[tm][tn][i] * dv[i]);
            }
        }
    }
}

// ---------------- CSR aggregation, fused self-loop + dinv + bias --------------
// OUT[d] = dinv[d] * (HS[d] + sum_{s in N(d)} HS[s]) + bias;  HS is bf16.
// 16 threads per node, 8 channels each.
template <bool OUT_BF16>
__global__ __launch_bounds__(256) void aggregate_csr(const ushort* __restrict__ HS,
                                                     const int* __restrict__ rowptr,
                                                     const int* __restrict__ csr,
                                                     const float* __restrict__ dinv,
                                                     const float* __restrict__ bias,
                                                     void* __restrict__ OUT, int n) {
    int d = blockIdx.x * 16 + (threadIdx.x >> 4);
    if (d >= n) return;
    int j = threadIdx.x & 15;

    float acc[8];
    {
        short8 v = *(const short8*)(HS + (size_t)d * CC + j * 8);
#pragma unroll
        for (int i = 0; i < 8; ++i) acc[i] = bf2f((ushort)v[i]);
    }
    int k = rowptr[d], end = rowptr[d + 1];
    for (; k < end; ++k) {
        int s = csr[k];
        short8 v = *(const short8*)(HS + (size_t)s * CC + j * 8);
#pragma unroll
        for (int i = 0; i < 8; ++i) acc[i] += bf2f((ushort)v[i]);
    }
    float dd = dinv[d];
    float4 b0 = ((const float4*)bias)[j * 2];
    float4 b1 = ((const float4*)bias)[j * 2 + 1];
    float o[8];
    o[0] = fmaf(acc[0], dd, b0.x); o[1] = fmaf(acc[1], dd, b0.y);
    o[2] = fmaf(acc[2], dd, b0.z); o[3] = fmaf(acc[3], dd, b0.w);
    o[4] = fmaf(acc[4], dd, b1.x); o[5] = fmaf(acc[5], dd, b1.y);
    o[6] = fmaf(acc[6], dd, b1.z); o[7] = fmaf(acc[7], dd, b1.w);

    if constexpr (OUT_BF16) {
        short8 v;
#pragma unroll
        for (int i = 0; i < 8; ++i) v[i] = (short)f2bf(o[i]);
        *(short8*)((ushort*)OUT + (size_t)d * CC + j * 8) = v;
    } else {
        float* op = (float*)OUT + (size_t)d * CC + j * 8;
        ((float4*)op)[0] = float4{o[0], o[1], o[2], o[3]};
        ((float4*)op)[1] = float4{o[4], o[5], o[6], o[7]};
    }
}

// ---------------- BN column stats (bf16 input) ----------------
__global__ __launch_bounds__(256) void bn_stats(const ushort* __restrict__ X,
                                                float* __restrict__ sums, int n) {
    int c = threadIdx.x & 127;
    int rs = threadIdx.x >> 7;
    float s = 0.f, q = 0.f;
    for (int r = blockIdx.x * 2 + rs; r < n; r += gridDim.x * 2) {
        float v = bf2f(X[(size_t)r * CC + c]);
        s += v;
        q = fmaf(v, v, q);
    }
    atomicAdd(&sums[c], s);
    atomicAdd(&sums[CC + c], q);
}

// ---------------- BN + ReLU (bf16 in, bf16 out, in-place safe) ----------------
__global__ __launch_bounds__(256) void bn_relu(ushort* __restrict__ X,
                                               const float* __restrict__ sums,
                                               const float* __restrict__ gamma,
                                               const float* __restrict__ beta, int n) {
    int t = blockIdx.x * 256 + threadIdx.x;
    int tot8 = n * (CC / 8);
    if (t >= tot8) return;
    int j = t & 15;                       // 8-channel group
    float inv_n = 1.0f / (float)n;
    short8 v = *(const short8*)(X + (size_t)t * 8);
    float sm[8], sq[8], g[8], be[8];
    {
        float4 a = ((const float4*)sums)[j * 2];
        float4 b = ((const float4*)sums)[j * 2 + 1];
        sm[0]=a.x; sm[1]=a.y; sm[2]=a.z; sm[3]=a.w; sm[4]=b.x; sm[5]=b.y; sm[6]=b.z; sm[7]=b.w;
        a = ((const float4*)(sums + CC))[j * 2];
        b = ((const float4*)(sums + CC))[j * 2 + 1];
        sq[0]=a.x; sq[1]=a.y; sq[2]=a.z; sq[3]=a.w; sq[4]=b.x; sq[5]=b.y; sq[6]=b.z; sq[7]=b.w;
        a = ((const float4*)gamma)[j * 2];
        b = ((const float4*)gamma)[j * 2 + 1];
        g[0]=a.x; g[1]=a.y; g[2]=a.z; g[3]=a.w; g[4]=b.x; g[5]=b.y; g[6]=b.z; g[7]=b.w;
        a = ((const float4*)beta)[j * 2];
        b = ((const float4*)beta)[j * 2 + 1];
        be[0]=a.x; be[1]=a.y; be[2]=a.z; be[3]=a.w; be[4]=b.x; be[5]=b.y; be[6]=b.z; be[7]=b.w;
    }
    short8 y;
#pragma unroll
    for (int i = 0; i < 8; ++i) {
        float mean = sm[i] * inv_n;
        float var = sq[i] * inv_n - mean * mean;
        float sc = g[i] * rsqrtf(var + 1e-5f);
        float r = fmaxf(0.f, (bf2f((ushort)v[i]) - mean) * sc + be[i]);
        y[i] = (short)f2bf(r);
    }
    *(short8*)(X + (size_t)t * 8) = y;
}

extern "C" void kernel_launch(void* const* d_in, const int* in_sizes, int n_in,
                              void* d_out, int out_size, void* d_ws, size_t ws_size,
                              hipStream_t stream) {
    const float* x      = (const float*)d_in[0];
    const float* W1     = (const float*)d_in[1];
    const float* b1     = (const float*)d_in[2];
    const float* gamma1 = (const float*)d_in[3];
    const float* beta1  = (const float*)d_in[4];
    const float* W2     = (const float*)d_in[5];
    const float* b2     = (const float*)d_in[6];
    const int*   edge   = (const int*)d_in[7];

    int n = in_sizes[0] / CC;
    int e = in_sizes[7] / 2;
    const int* src = edge;
    const int* dst = edge + e;

    float* out = (float*)d_out;
    char* ws = (char*)d_ws;
    ushort* hs   = (ushort*)ws;  ws += (size_t)n * CC * 2;   // gemm out (bf16)
    ushort* A    = (ushort*)ws;  ws += (size_t)n * CC * 2;   // agg1 out / bn (bf16)
    ushort* Wt1  = (ushort*)ws;  ws += CC * CC * 2;
    ushort* Wt2  = (ushort*)ws;  ws += CC * CC * 2;
    int*   deg    = (int*)ws;    ws += (size_t)n * 4;
    float* dinv   = (float*)ws;  ws += (size_t)n * 4;
    int*   rowptr = (int*)ws;    ws += (size_t)(n + 1) * 4;
    int*   cursor = (int*)ws;    ws += (size_t)n * 4;
    int*   csr    = (int*)ws;    ws += (size_t)e * 4;
    int*   tsum   = (int*)ws;    ws += 4096;
    float* sums   = (float*)ws;

    int ntiles = (n + TILE - 1) / TILE;
    int gemm_grid = (n + CC - 1) / CC;
    int agg_grid = (n + 15) / 16;
    int tot8 = n * (CC / 8);

    // ---- graph structure ----
    hipMemsetAsync(deg, 0, (size_t)n * 4, stream);
    count_deg<<<(e + 255) / 256, 256, 0, stream>>>(dst, deg, e);
    make_dinv<<<(n + 255) / 256, 256, 0, stream>>>(deg, dinv, n);
    scan_tile_sums<<<ntiles, 256, 0, stream>>>(deg, tsum, n);
    scan_tops<<<1, 128, 0, stream>>>(tsum, ntiles);
    scan_final<<<ntiles, 256, 0, stream>>>(deg, tsum, rowptr, cursor, n);
    fill_csr<<<(e + 255) / 256, 256, 0, stream>>>(src, dst, cursor, csr, e);

    // ---- weights -> bf16 transposed ----
    convert_wT<<<64, 256, 0, stream>>>(W1, Wt1);
    convert_wT<<<64, 256, 0, stream>>>(W2, Wt2);

    // ---- layer 1 ----
    gemm_mfma<float><<<gemm_grid, 256, 0, stream>>>(x, Wt1, dinv, hs, n);
    aggregate_csr<true><<<agg_grid, 256, 0, stream>>>(hs, rowptr, csr, dinv, b1, A, n);

    // ---- batchnorm + relu (in-place on A) ----
    hipMemsetAsync(sums, 0, 2 * CC * 4, stream);
    bn_stats<<<512, 256, 0, stream>>>(A, sums, n);
    bn_relu<<<(tot8 + 255) / 256, 256, 0, stream>>>(A, sums, gamma1, beta1, n);

    // ---- layer 2 ----
    gemm_mfma<ushort><<<gemm_grid, 256, 0, stream>>>(A, Wt2, dinv, hs, n);
    aggregate_csr<false><<<agg_grid, 256, 0, stream>>>(hs, rowptr, csr, dinv, b2, out, n);
}